// Round 1
// baseline (501.157 us; speedup 1.0000x reference)
//
#include <hip/hip_runtime.h>

#define NDOCS 64
#define NPASS 1024
#define TITLE_LEN 128
#define SEQ 256
#define NEDGES 32768
#define NNODES 2112   // NDOCS + 2*NPASS
#define DIM 768
#define SPAN_TOK 30522
#define NREL 2

// ---------- build node features: x[2112][768] ----------
__global__ __launch_bounds__(256) void build_x_kernel(
    const int* __restrict__ doc_ids, const int* __restrict__ pass_ids,
    const float* __restrict__ embed, float* __restrict__ x) {
  int node = blockIdx.x;
  int tok;
  if (node < NDOCS) tok = doc_ids[node * TITLE_LEN];
  else if (node < NDOCS + NPASS) tok = pass_ids[(node - NDOCS) * SEQ];
  else tok = SPAN_TOK;  // span positions always hold SPAN_TOK by construction
  const float* e = embed + (size_t)tok * DIM;
  float* xr = x + (size_t)node * DIM;
  for (int j = threadIdx.x; j < DIM; j += blockDim.x) xr[j] = e[j];
}

// ---------- edge aggregation: num[r][dst] += x[src], cnt[r][dst] += 1 ----------
__global__ __launch_bounds__(256) void aggregate_kernel(
    const float* __restrict__ x, const int* __restrict__ src,
    const int* __restrict__ dst, const int* __restrict__ etype,
    float* __restrict__ num, float* __restrict__ cnt) {
  int e = blockIdx.x;
  int s = src[e], d = dst[e], r = etype[e];
  const float* xr = x + (size_t)s * DIM;
  float* nr = num + ((size_t)r * NNODES + d) * DIM;
  for (int j = threadIdx.x; j < DIM; j += blockDim.x)
    atomicAdd(&nr[j], xr[j]);
  if (threadIdx.x == 0) atomicAdd(&cnt[r * NNODES + d], 1.0f);
}

// ---------- divide sums by counts (in place) ----------
__global__ __launch_bounds__(256) void avg_kernel(float* __restrict__ num,
                                                  const float* __restrict__ cnt) {
  int row = blockIdx.x;  // 0 .. NREL*NNODES-1
  float inv = 1.0f / fmaxf(cnt[row], 1.0f);
  float* nr = num + (size_t)row * DIM;
  for (int j = threadIdx.x; j < DIM; j += blockDim.x) nr[j] *= inv;
}

// ---------- fp32 tiled matmul: C[2112,768] (+)= A[2112,768] @ B[768,768] ----------
// BM=BN=64, BK=16, 256 threads, 4x4 per thread. INIT=1: C = A@B + bias; INIT=0: C += A@B
template <int INIT>
__global__ __launch_bounds__(256) void mm_kernel(const float* __restrict__ A,
                                                 const float* __restrict__ B,
                                                 const float* __restrict__ bias,
                                                 float* __restrict__ C) {
  __shared__ float As[16][64];
  __shared__ float Bs[16][64];
  int tid = threadIdx.x;
  int tx = tid & 15, ty = tid >> 4;
  int row0 = blockIdx.x * 64;
  int col0 = blockIdx.y * 64;
  float acc[4][4] = {};
  for (int k0 = 0; k0 < DIM; k0 += 16) {
    // load A tile 64x16 (transposed into LDS)
    {
      int r = tid >> 2;
      int kk = (tid & 3) * 4;
      const float4 av =
          *reinterpret_cast<const float4*>(&A[(size_t)(row0 + r) * DIM + k0 + kk]);
      As[kk + 0][r] = av.x;
      As[kk + 1][r] = av.y;
      As[kk + 2][r] = av.z;
      As[kk + 3][r] = av.w;
    }
    // load B tile 16x64
    {
      int kk = tid >> 4;
      int c = (tid & 15) * 4;
      const float4 bv =
          *reinterpret_cast<const float4*>(&B[(size_t)(k0 + kk) * DIM + col0 + c]);
      *reinterpret_cast<float4*>(&Bs[kk][c]) = bv;
    }
    __syncthreads();
#pragma unroll
    for (int kk = 0; kk < 16; ++kk) {
      float a[4], b[4];
#pragma unroll
      for (int i = 0; i < 4; i++) a[i] = As[kk][ty * 4 + i];
#pragma unroll
      for (int j = 0; j < 4; j++) b[j] = Bs[kk][tx * 4 + j];
#pragma unroll
      for (int i = 0; i < 4; i++)
#pragma unroll
        for (int j = 0; j < 4; j++) acc[i][j] += a[i] * b[j];
    }
    __syncthreads();
  }
#pragma unroll
  for (int i = 0; i < 4; i++) {
    int row = row0 + ty * 4 + i;
#pragma unroll
    for (int j = 0; j < 4; j++) {
      int col = col0 + tx * 4 + j;
      float v = acc[i][j];
      if (INIT) {
        C[(size_t)row * DIM + col] = v + bias[col];
      } else {
        C[(size_t)row * DIM + col] += v;
      }
    }
  }
}

// ---------- classifier over the last NPASS (span) rows ----------
__global__ __launch_bounds__(256) void classify_kernel(
    const float* __restrict__ x, const float* __restrict__ clf_w,
    const float* __restrict__ clf_b, float* __restrict__ out) {
  int i = blockIdx.x;
  const float* xr = x + (size_t)(NNODES - NPASS + i) * DIM;
  float s = 0.f;
  for (int j = threadIdx.x; j < DIM; j += blockDim.x) s += xr[j] * clf_w[j];
#pragma unroll
  for (int off = 32; off > 0; off >>= 1) s += __shfl_down(s, off);
  __shared__ float red[4];
  int wid = threadIdx.x >> 6;
  if ((threadIdx.x & 63) == 0) red[wid] = s;
  __syncthreads();
  if (threadIdx.x == 0) {
    float z = red[0] + red[1] + red[2] + red[3] + clf_b[0];
    float sc = 1.0f / (1.0f + expf(-z));
    out[i] = expf(sc * 5.0f);  // exp(score / TAU), TAU = 0.2
  }
}

extern "C" void kernel_launch(void* const* d_in, const int* in_sizes, int n_in,
                              void* d_out, int out_size, void* d_ws, size_t ws_size,
                              hipStream_t stream) {
  const int* doc_ids = (const int*)d_in[0];
  const int* pass_ids = (const int*)d_in[1];
  const int* edge_index = (const int*)d_in[2];
  const int* etype = (const int*)d_in[3];
  const float* embed = (const float*)d_in[4];
  const float* w_root1 = (const float*)d_in[5];
  const float* w_rel1 = (const float*)d_in[6];
  const float* b1 = (const float*)d_in[7];
  const float* w_root2 = (const float*)d_in[8];
  const float* w_rel2 = (const float*)d_in[9];
  const float* b2 = (const float*)d_in[10];
  const float* clf_w = (const float*)d_in[11];
  const float* clf_b = (const float*)d_in[12];
  float* out = (float*)d_out;

  float* ws = (float*)d_ws;
  float* xA = ws;                                     // NNODES*DIM
  float* xB = xA + (size_t)NNODES * DIM;              // NNODES*DIM
  float* num = xB + (size_t)NNODES * DIM;             // NREL*NNODES*DIM
  float* cnt = num + (size_t)NREL * NNODES * DIM;     // NREL*NNODES
  const size_t agg_bytes =
      ((size_t)NREL * NNODES * DIM + (size_t)NREL * NNODES) * sizeof(float);

  const int* src = edge_index;
  const int* dst = edge_index + NEDGES;

  dim3 mm_grid(NNODES / 64, DIM / 64);

  build_x_kernel<<<NNODES, 256, 0, stream>>>(doc_ids, pass_ids, embed, xA);

  // ---- layer 1: xA -> xB ----
  hipMemsetAsync(num, 0, agg_bytes, stream);
  aggregate_kernel<<<NEDGES, 256, 0, stream>>>(xA, src, dst, etype, num, cnt);
  avg_kernel<<<NREL * NNODES, 256, 0, stream>>>(num, cnt);
  mm_kernel<1><<<mm_grid, 256, 0, stream>>>(xA, w_root1, b1, xB);
  mm_kernel<0><<<mm_grid, 256, 0, stream>>>(num, w_rel1, nullptr, xB);
  mm_kernel<0><<<mm_grid, 256, 0, stream>>>(num + (size_t)NNODES * DIM,
                                            w_rel1 + DIM * DIM, nullptr, xB);

  // ---- layer 2: xB -> xA ----
  hipMemsetAsync(num, 0, agg_bytes, stream);
  aggregate_kernel<<<NEDGES, 256, 0, stream>>>(xB, src, dst, etype, num, cnt);
  avg_kernel<<<NREL * NNODES, 256, 0, stream>>>(num, cnt);
  mm_kernel<1><<<mm_grid, 256, 0, stream>>>(xB, w_root2, b2, xA);
  mm_kernel<0><<<mm_grid, 256, 0, stream>>>(num, w_rel2, nullptr, xA);
  mm_kernel<0><<<mm_grid, 256, 0, stream>>>(num + (size_t)NNODES * DIM,
                                            w_rel2 + DIM * DIM, nullptr, xA);

  classify_kernel<<<NPASS, 256, 0, stream>>>(xA, clf_w, clf_b, out);
}

// Round 2
// 144.781 us; speedup vs baseline: 3.4615x; 3.4615x over previous
//
#include <hip/hip_runtime.h>

#define NDOCS 64
#define NPASS 1024
#define TITLE_LEN 128
#define SEQ 256
#define NEDGES 32768
#define NNODES 2112   // NDOCS + 2*NPASS
#define DIM 768
#define KA 2304       // 3*DIM fused K
#define NPAD 2176     // 17 * 128
#define SPAN_TOK 30522
#define NREL 2
#define NBINS (NREL * NNODES)  // 4224
#define BK 64

typedef unsigned short u16;
typedef u16 u16x4 __attribute__((ext_vector_type(4)));
typedef __bf16 bf16x8 __attribute__((ext_vector_type(8)));
typedef float f32x4 __attribute__((ext_vector_type(4)));

__device__ inline u16 f2bf(float f) {
  unsigned u = __builtin_bit_cast(unsigned, f);
  u += 0x7FFFu + ((u >> 16) & 1u);
  return (u16)(u >> 16);
}
__device__ inline float bf2f(u16 h) {
  unsigned u = ((unsigned)h) << 16;
  return __builtin_bit_cast(float, u);
}
__device__ inline void gld16(const void* g, void* l) {
  __builtin_amdgcn_global_load_lds(
      (const __attribute__((address_space(1))) void*)g,
      (__attribute__((address_space(3))) void*)l, 16, 0, 0);
}

// ---------- node features -> bf16 x-slice of A1 ----------
__global__ __launch_bounds__(192) void build_x_kernel(
    const int* __restrict__ doc_ids, const int* __restrict__ pass_ids,
    const float* __restrict__ embed, u16* __restrict__ A1) {
  int node = blockIdx.x;
  int t = threadIdx.x;  // 192 threads x 4 cols
  int tok;
  if (node < NDOCS) tok = doc_ids[node * TITLE_LEN];
  else if (node < NDOCS + NPASS) tok = pass_ids[(node - NDOCS) * SEQ];
  else tok = SPAN_TOK;
  float4 v = *reinterpret_cast<const float4*>(&embed[(size_t)tok * DIM + t * 4]);
  u16x4 o;
  o.x = f2bf(v.x); o.y = f2bf(v.y); o.z = f2bf(v.z); o.w = f2bf(v.w);
  *reinterpret_cast<u16x4*>(&A1[(size_t)node * KA + t * 4]) = o;
}

// ---------- CSR build ----------
__global__ __launch_bounds__(256) void hist_kernel(const int* __restrict__ dst,
                                                   const int* __restrict__ et,
                                                   int* __restrict__ deg) {
  int e = blockIdx.x * 256 + threadIdx.x;
  atomicAdd(&deg[et[e] * NNODES + dst[e]], 1);
}

__global__ __launch_bounds__(256) void scan_kernel(const int* __restrict__ deg,
                                                   int* __restrict__ offs,
                                                   int* __restrict__ cur) {
  __shared__ int part[256];
  int t = threadIdx.x;
  int loc[17];
  int s = 0;
#pragma unroll
  for (int i = 0; i < 17; ++i) {
    int idx = t * 17 + i;
    loc[i] = s;
    s += (idx < NBINS) ? deg[idx] : 0;
  }
  part[t] = s;
  __syncthreads();
  for (int off = 1; off < 256; off <<= 1) {
    int v = (t >= off) ? part[t - off] : 0;
    __syncthreads();
    part[t] += v;
    __syncthreads();
  }
  int pre = (t == 0) ? 0 : part[t - 1];
#pragma unroll
  for (int i = 0; i < 17; ++i) {
    int idx = t * 17 + i;
    if (idx <= NBINS) {
      int v = pre + loc[i];
      offs[idx] = v;
      if (idx < NBINS) cur[idx] = v;
    }
  }
}

__global__ __launch_bounds__(256) void scatter_kernel(
    const int* __restrict__ srcv, const int* __restrict__ dst,
    const int* __restrict__ et, int* __restrict__ cur, int* __restrict__ perm) {
  int e = blockIdx.x * 256 + threadIdx.x;
  int bin = et[e] * NNODES + dst[e];
  int p = atomicAdd(&cur[bin], 1);
  perm[p] = srcv[e];
}

// ---------- per-bin mean gather: A num-slices (bf16, no atomics) ----------
__global__ __launch_bounds__(192) void gather_kernel(const u16* __restrict__ A,
                                                     const int* __restrict__ offs,
                                                     const int* __restrict__ perm,
                                                     u16* __restrict__ Anum) {
  int bin = blockIdx.x;  // r*NNODES + d
  int r = bin / NNODES;
  int d = bin - r * NNODES;
  int beg = offs[bin], end = offs[bin + 1];
  int t = threadIdx.x;
  float a0 = 0.f, a1 = 0.f, a2 = 0.f, a3 = 0.f;
  for (int i = beg; i < end; ++i) {
    int s = perm[i];
    u16x4 v = *reinterpret_cast<const u16x4*>(&A[(size_t)s * KA + t * 4]);
    a0 += bf2f(v.x); a1 += bf2f(v.y); a2 += bf2f(v.z); a3 += bf2f(v.w);
  }
  float inv = (end > beg) ? 1.0f / (float)(end - beg) : 0.0f;
  u16x4 o;
  o.x = f2bf(a0 * inv); o.y = f2bf(a1 * inv); o.z = f2bf(a2 * inv); o.w = f2bf(a3 * inv);
  *reinterpret_cast<u16x4*>(&Anum[(size_t)d * KA + DIM + (size_t)r * DIM + t * 4]) = o;
}

// ---------- weights -> Bt (N x K bf16, transposed) ----------
__global__ __launch_bounds__(256) void conv_bt_kernel(
    const float* __restrict__ w_root, const float* __restrict__ w_rel,
    u16* __restrict__ Bt) {
  __shared__ float tile[32][33];
  int k0 = blockIdx.x * 32, n0 = blockIdx.y * 32;
  int tx = threadIdx.x & 31, ty = threadIdx.x >> 5;  // 32 x 8
#pragma unroll
  for (int i = 0; i < 4; ++i) {
    int k = k0 + ty + 8 * i;
    const float* row = (k < DIM) ? (w_root + (size_t)k * DIM)
                                 : (w_rel + (size_t)(k - DIM) * DIM);
    tile[ty + 8 * i][tx] = row[n0 + tx];
  }
  __syncthreads();
#pragma unroll
  for (int i = 0; i < 4; ++i) {
    int n = n0 + ty + 8 * i;
    Bt[(size_t)n * KA + k0 + tx] = f2bf(tile[tx][ty + 8 * i]);
  }
}

// ---------- bf16 MFMA GEMM: C[npad x 768] = A[npad x 2304] @ Bt^T + bias ----------
// 128x128 tile, BK=64, 4 waves (2x2), 16x16x32 mfma, XOR-swizzled LDS.
__global__ __launch_bounds__(256) void gemm_kernel(
    const u16* __restrict__ A, const u16* __restrict__ Bt,
    const float* __restrict__ bias, u16* __restrict__ C /* ldc = KA */) {
  __shared__ u16 As[128 * BK];
  __shared__ u16 Bs[128 * BK];
  int tid = threadIdx.x;
  int lane = tid & 63, wid = tid >> 6;
  int wr = wid >> 1, wc = wid & 1;
  int row0 = blockIdx.x * 128, col0 = blockIdx.y * 128;
  int l15 = lane & 15, l4 = lane >> 4;
  int rc = lane >> 3;    // row within 8-row staging chunk
  int c2s = lane & 7;    // 16B slot within row
  f32x4 acc[4][4] = {};
  for (int k0 = 0; k0 < KA; k0 += BK) {
#pragma unroll
    for (int h = 0; h < 4; ++h) {
      int c = wid * 4 + h;       // chunk 0..15 (1 KB each)
      int r = c * 8 + rc;        // tile row 0..127
      int kk = (c2s ^ (r & 7)) * 8;  // pre-swizzled global source
      gld16(&A[(size_t)(row0 + r) * KA + k0 + kk], &As[c * 512 + lane * 8]);
      gld16(&Bt[(size_t)(col0 + r) * KA + k0 + kk], &Bs[c * 512 + lane * 8]);
    }
    __syncthreads();
    bf16x8 af[2][4], bg[2][4];
#pragma unroll
    for (int h = 0; h < 2; ++h) {
#pragma unroll
      for (int m = 0; m < 4; ++m) {
        int rl = wr * 64 + m * 16 + l15;
        int ck = (h * 4 + l4) ^ (rl & 7);
        af[h][m] = *reinterpret_cast<const bf16x8*>(&As[rl * BK + ck * 8]);
        int cl = wc * 64 + m * 16 + l15;
        int ck2 = (h * 4 + l4) ^ (cl & 7);
        bg[h][m] = *reinterpret_cast<const bf16x8*>(&Bs[cl * BK + ck2 * 8]);
      }
    }
#pragma unroll
    for (int h = 0; h < 2; ++h)
#pragma unroll
      for (int m = 0; m < 4; ++m)
#pragma unroll
        for (int n = 0; n < 4; ++n)
          acc[m][n] = __builtin_amdgcn_mfma_f32_16x16x32_bf16(af[h][m], bg[h][n],
                                                              acc[m][n], 0, 0, 0);
    __syncthreads();
  }
#pragma unroll
  for (int m = 0; m < 4; ++m) {
#pragma unroll
    for (int n = 0; n < 4; ++n) {
      int col = col0 + wc * 64 + n * 16 + l15;
      float b = bias[col];
#pragma unroll
      for (int q = 0; q < 4; ++q) {
        int row = row0 + wr * 64 + m * 16 + l4 * 4 + q;
        C[(size_t)row * KA + col] = f2bf(acc[m][n][q] + b);
      }
    }
  }
}

// ---------- classifier over span rows ----------
__global__ __launch_bounds__(192) void classify_kernel(
    const u16* __restrict__ x, const float* __restrict__ clf_w,
    const float* __restrict__ clf_b, float* __restrict__ out) {
  int i = blockIdx.x;
  int t = threadIdx.x;
  const u16* xr = x + (size_t)(NNODES - NPASS + i) * KA;
  u16x4 v = *reinterpret_cast<const u16x4*>(&xr[t * 4]);
  float4 w = *reinterpret_cast<const float4*>(&clf_w[t * 4]);
  float s = bf2f(v.x) * w.x + bf2f(v.y) * w.y + bf2f(v.z) * w.z + bf2f(v.w) * w.w;
#pragma unroll
  for (int off = 32; off > 0; off >>= 1) s += __shfl_down(s, off);
  __shared__ float red[3];
  if ((t & 63) == 0) red[t >> 6] = s;
  __syncthreads();
  if (t == 0) {
    float z = red[0] + red[1] + red[2] + clf_b[0];
    float sc = 1.0f / (1.0f + expf(-z));
    out[i] = expf(sc * 5.0f);  // exp(score / TAU), TAU = 0.2
  }
}

extern "C" void kernel_launch(void* const* d_in, const int* in_sizes, int n_in,
                              void* d_out, int out_size, void* d_ws, size_t ws_size,
                              hipStream_t stream) {
  const int* doc_ids = (const int*)d_in[0];
  const int* pass_ids = (const int*)d_in[1];
  const int* edge_index = (const int*)d_in[2];
  const int* etype = (const int*)d_in[3];
  const float* embed = (const float*)d_in[4];
  const float* w_root1 = (const float*)d_in[5];
  const float* w_rel1 = (const float*)d_in[6];
  const float* b1 = (const float*)d_in[7];
  const float* w_root2 = (const float*)d_in[8];
  const float* w_rel2 = (const float*)d_in[9];
  const float* b2 = (const float*)d_in[10];
  const float* clf_w = (const float*)d_in[11];
  const float* clf_b = (const float*)d_in[12];
  float* out = (float*)d_out;

  const int* src = edge_index;
  const int* dst = edge_index + NEDGES;

  u16* A1 = (u16*)d_ws;                      // NPAD * KA bf16
  u16* A2 = A1 + (size_t)NPAD * KA;          // NPAD * KA bf16
  u16* Bt = A2 + (size_t)NPAD * KA;          // 768 * KA bf16
  int* deg = (int*)(Bt + (size_t)DIM * KA);  // NBINS
  int* offs = deg + NBINS;                   // NBINS + 1
  int* cur = offs + NBINS + 1;               // NBINS
  int* perm = cur + NBINS;                   // NEDGES

  // CSR of edges by (rel, dst)
  hipMemsetAsync(deg, 0, NBINS * sizeof(int), stream);
  hist_kernel<<<NEDGES / 256, 256, 0, stream>>>(dst, etype, deg);
  scan_kernel<<<1, 256, 0, stream>>>(deg, offs, cur);
  scatter_kernel<<<NEDGES / 256, 256, 0, stream>>>(src, dst, etype, cur, perm);

  // layer 1
  build_x_kernel<<<NNODES, 192, 0, stream>>>(doc_ids, pass_ids, embed, A1);
  gather_kernel<<<NBINS, 192, 0, stream>>>(A1, offs, perm, A1);
  conv_bt_kernel<<<dim3(KA / 32, DIM / 32), 256, 0, stream>>>(w_root1, w_rel1, Bt);
  gemm_kernel<<<dim3(NPAD / 128, DIM / 128), 256, 0, stream>>>(A1, Bt, b1, A2);

  // layer 2
  gather_kernel<<<NBINS, 192, 0, stream>>>(A2, offs, perm, A2);
  conv_bt_kernel<<<dim3(KA / 32, DIM / 32), 256, 0, stream>>>(w_root2, w_rel2, Bt);
  gemm_kernel<<<dim3(NPAD / 128, DIM / 128), 256, 0, stream>>>(A2, Bt, b2, A1);

  classify_kernel<<<NPASS, 192, 0, stream>>>(A1, clf_w, clf_b, out);
}

// Round 3
// 105.323 us; speedup vs baseline: 4.7583x; 1.3746x over previous
//
#include <hip/hip_runtime.h>

#define NDOCS 64
#define NPASS 1024
#define TITLE_LEN 128
#define SEQ 256
#define NEDGES 32768
#define NNODES 2112   // NDOCS + 2*NPASS
#define DIM 768
#define KA 2304       // 3*DIM fused K
#define NPAD 2176     // 34 * 64
#define SPAN_TOK 30522
#define NREL 2
#define NBINS (NREL * NNODES)  // 4224
#define BK 64

typedef unsigned short u16;
typedef u16 u16x4 __attribute__((ext_vector_type(4)));
typedef __bf16 bf16x8 __attribute__((ext_vector_type(8)));
typedef float f32x4 __attribute__((ext_vector_type(4)));

__device__ inline u16 f2bf(float f) {
  unsigned u = __builtin_bit_cast(unsigned, f);
  u += 0x7FFFu + ((u >> 16) & 1u);
  return (u16)(u >> 16);
}
__device__ inline float bf2f(u16 h) {
  unsigned u = ((unsigned)h) << 16;
  return __builtin_bit_cast(float, u);
}
__device__ inline void gld16(const void* g, void* l) {
  __builtin_amdgcn_global_load_lds(
      (const __attribute__((address_space(1))) void*)g,
      (__attribute__((address_space(3))) void*)l, 16, 0, 0);
}

// ---------- node features -> bf16 x-slice of A1 ----------
__global__ __launch_bounds__(192) void build_x_kernel(
    const int* __restrict__ doc_ids, const int* __restrict__ pass_ids,
    const float* __restrict__ embed, u16* __restrict__ A1) {
  int node = blockIdx.x;
  int t = threadIdx.x;  // 192 threads x 4 cols
  int tok;
  if (node < NDOCS) tok = doc_ids[node * TITLE_LEN];
  else if (node < NDOCS + NPASS) tok = pass_ids[(node - NDOCS) * SEQ];
  else tok = SPAN_TOK;
  float4 v = *reinterpret_cast<const float4*>(&embed[(size_t)tok * DIM + t * 4]);
  u16x4 o;
  o.x = f2bf(v.x); o.y = f2bf(v.y); o.z = f2bf(v.z); o.w = f2bf(v.w);
  *reinterpret_cast<u16x4*>(&A1[(size_t)node * KA + t * 4]) = o;
}

// ---------- CSR build ----------
__global__ __launch_bounds__(256) void clear_deg_kernel(int* __restrict__ deg) {
  int i = blockIdx.x * 256 + threadIdx.x;
  if (i < NBINS) deg[i] = 0;
}

__global__ __launch_bounds__(256) void hist_kernel(const int* __restrict__ dst,
                                                   const int* __restrict__ et,
                                                   int* __restrict__ deg) {
  int e = blockIdx.x * 256 + threadIdx.x;
  atomicAdd(&deg[et[e] * NNODES + dst[e]], 1);
}

__global__ __launch_bounds__(256) void scan_kernel(const int* __restrict__ deg,
                                                   int* __restrict__ offs,
                                                   int* __restrict__ cur) {
  __shared__ int part[256];
  int t = threadIdx.x;
  int loc[17];
  int s = 0;
#pragma unroll
  for (int i = 0; i < 17; ++i) {
    int idx = t * 17 + i;
    loc[i] = s;
    s += (idx < NBINS) ? deg[idx] : 0;
  }
  part[t] = s;
  __syncthreads();
  for (int off = 1; off < 256; off <<= 1) {
    int v = (t >= off) ? part[t - off] : 0;
    __syncthreads();
    part[t] += v;
    __syncthreads();
  }
  int pre = (t == 0) ? 0 : part[t - 1];
#pragma unroll
  for (int i = 0; i < 17; ++i) {
    int idx = t * 17 + i;
    if (idx <= NBINS) {
      int v = pre + loc[i];
      offs[idx] = v;
      if (idx < NBINS) cur[idx] = v;
    }
  }
}

__global__ __launch_bounds__(256) void scatter_kernel(
    const int* __restrict__ srcv, const int* __restrict__ dst,
    const int* __restrict__ et, int* __restrict__ cur, int* __restrict__ perm) {
  int e = blockIdx.x * 256 + threadIdx.x;
  int bin = et[e] * NNODES + dst[e];
  int p = atomicAdd(&cur[bin], 1);
  perm[p] = srcv[e];
}

// ---------- per-bin mean gather: A num-slices (bf16, no atomics) ----------
__global__ __launch_bounds__(192) void gather_kernel(const u16* __restrict__ A,
                                                     const int* __restrict__ offs,
                                                     const int* __restrict__ perm,
                                                     u16* __restrict__ Anum) {
  int bin = blockIdx.x;  // r*NNODES + d
  int r = bin / NNODES;
  int d = bin - r * NNODES;
  int beg = offs[bin], end = offs[bin + 1];
  int t = threadIdx.x;
  float a0 = 0.f, a1 = 0.f, a2 = 0.f, a3 = 0.f;
  for (int i = beg; i < end; ++i) {
    int s = perm[i];
    u16x4 v = *reinterpret_cast<const u16x4*>(&A[(size_t)s * KA + t * 4]);
    a0 += bf2f(v.x); a1 += bf2f(v.y); a2 += bf2f(v.z); a3 += bf2f(v.w);
  }
  float inv = (end > beg) ? 1.0f / (float)(end - beg) : 0.0f;
  u16x4 o;
  o.x = f2bf(a0 * inv); o.y = f2bf(a1 * inv); o.z = f2bf(a2 * inv); o.w = f2bf(a3 * inv);
  *reinterpret_cast<u16x4*>(&Anum[(size_t)d * KA + DIM + (size_t)r * DIM + t * 4]) = o;
}

// ---------- weights -> Bt (N x K bf16, transposed) ----------
__global__ __launch_bounds__(256) void conv_bt_kernel(
    const float* __restrict__ w_root, const float* __restrict__ w_rel,
    u16* __restrict__ Bt) {
  __shared__ float tile[32][33];
  int k0 = blockIdx.x * 32, n0 = blockIdx.y * 32;
  int tx = threadIdx.x & 31, ty = threadIdx.x >> 5;  // 32 x 8
#pragma unroll
  for (int i = 0; i < 4; ++i) {
    int k = k0 + ty + 8 * i;
    const float* row = (k < DIM) ? (w_root + (size_t)k * DIM)
                                 : (w_rel + (size_t)(k - DIM) * DIM);
    tile[ty + 8 * i][tx] = row[n0 + tx];
  }
  __syncthreads();
#pragma unroll
  for (int i = 0; i < 4; ++i) {
    int n = n0 + ty + 8 * i;
    Bt[(size_t)n * KA + k0 + tx] = f2bf(tile[tx][ty + 8 * i]);
  }
}

// ---------- bf16 MFMA GEMM: C[NPAD x 768] = A[NPAD x 2304] @ Bt^T + bias ----------
// 64x64 tile, BK=64, 4 waves (2x2, 32x32 each), double-buffered LDS, 2-phase
// prefetch (stage t+1 before computing t), XCD-swizzled 1D grid of 408.
__global__ __launch_bounds__(256) void gemm_kernel(
    const u16* __restrict__ A, const u16* __restrict__ Bt,
    const float* __restrict__ bias, u16* __restrict__ C /* ldc = KA */) {
  __shared__ u16 As[2][64 * BK];
  __shared__ u16 Bs[2][64 * BK];
  int wg = blockIdx.x;                     // 0..407, 408 = 8 XCDs * 51
  int swz = (wg & 7) * 51 + (wg >> 3);     // bijective: contiguous tiles per XCD
  int bm = swz / 12, bn = swz % 12;        // 34 x 12 tile grid
  int row0 = bm * 64, col0 = bn * 64;
  int tid = threadIdx.x;
  int lane = tid & 63, wid = tid >> 6;
  int wr = wid >> 1, wc = wid & 1;
  int l15 = lane & 15, l4 = lane >> 4;
  int sr = tid >> 3;  // staging row within 32-row chunk
  int sc = tid & 7;   // staging 16B slot
  f32x4 acc[2][2] = {};

#define STAGE(b, kbase)                                                         \
  {                                                                             \
    _Pragma("unroll") for (int h = 0; h < 2; ++h) {                             \
      int r = h * 32 + sr;                                                      \
      int kk = (sc ^ (r & 7)) * 8; /* pre-swizzled global source (rule #21) */  \
      gld16(&A[(size_t)(row0 + r) * KA + (kbase) + kk],                         \
            &As[b][h * 2048 + tid * 8]);                                        \
      gld16(&Bt[(size_t)(col0 + r) * KA + (kbase) + kk],                        \
            &Bs[b][h * 2048 + tid * 8]);                                        \
    }                                                                           \
  }

  STAGE(0, 0);
  __syncthreads();  // implicit vmcnt(0) drain: buf0 ready

  const int nt = KA / BK;  // 36
  for (int t = 0; t < nt; ++t) {
    int buf = t & 1;
    if (t + 1 < nt) STAGE(buf ^ 1, (t + 1) * BK);  // prefetch next tile
    bf16x8 af[2][2], bg[2][2];
#pragma unroll
    for (int h = 0; h < 2; ++h) {
#pragma unroll
      for (int m = 0; m < 2; ++m) {
        int rl = wr * 32 + m * 16 + l15;
        int ck = (h * 4 + l4) ^ (rl & 7);
        af[h][m] = *reinterpret_cast<const bf16x8*>(&As[buf][rl * BK + ck * 8]);
        int cl = wc * 32 + m * 16 + l15;
        int ck2 = (h * 4 + l4) ^ (cl & 7);
        bg[h][m] = *reinterpret_cast<const bf16x8*>(&Bs[buf][cl * BK + ck2 * 8]);
      }
    }
#pragma unroll
    for (int h = 0; h < 2; ++h)
#pragma unroll
      for (int m = 0; m < 2; ++m)
#pragma unroll
        for (int n = 0; n < 2; ++n)
          acc[m][n] = __builtin_amdgcn_mfma_f32_16x16x32_bf16(af[h][m], bg[h][n],
                                                              acc[m][n], 0, 0, 0);
    __syncthreads();  // drains prefetch vmcnt + protects buf reuse
  }
#undef STAGE

#pragma unroll
  for (int m = 0; m < 2; ++m) {
#pragma unroll
    for (int n = 0; n < 2; ++n) {
      int col = col0 + wc * 32 + n * 16 + l15;
      float b = bias[col];
#pragma unroll
      for (int q = 0; q < 4; ++q) {
        int row = row0 + wr * 32 + m * 16 + l4 * 4 + q;
        C[(size_t)row * KA + col] = f2bf(acc[m][n][q] + b);
      }
    }
  }
}

// ---------- classifier over span rows ----------
__global__ __launch_bounds__(192) void classify_kernel(
    const u16* __restrict__ x, const float* __restrict__ clf_w,
    const float* __restrict__ clf_b, float* __restrict__ out) {
  int i = blockIdx.x;
  int t = threadIdx.x;
  const u16* xr = x + (size_t)(NNODES - NPASS + i) * KA;
  u16x4 v = *reinterpret_cast<const u16x4*>(&xr[t * 4]);
  float4 w = *reinterpret_cast<const float4*>(&clf_w[t * 4]);
  float s = bf2f(v.x) * w.x + bf2f(v.y) * w.y + bf2f(v.z) * w.z + bf2f(v.w) * w.w;
#pragma unroll
  for (int off = 32; off > 0; off >>= 1) s += __shfl_down(s, off);
  __shared__ float red[3];
  if ((t & 63) == 0) red[t >> 6] = s;
  __syncthreads();
  if (t == 0) {
    float z = red[0] + red[1] + red[2] + clf_b[0];
    float sc = 1.0f / (1.0f + expf(-z));
    out[i] = expf(sc * 5.0f);  // exp(score / TAU), TAU = 0.2
  }
}

extern "C" void kernel_launch(void* const* d_in, const int* in_sizes, int n_in,
                              void* d_out, int out_size, void* d_ws, size_t ws_size,
                              hipStream_t stream) {
  const int* doc_ids = (const int*)d_in[0];
  const int* pass_ids = (const int*)d_in[1];
  const int* edge_index = (const int*)d_in[2];
  const int* etype = (const int*)d_in[3];
  const float* embed = (const float*)d_in[4];
  const float* w_root1 = (const float*)d_in[5];
  const float* w_rel1 = (const float*)d_in[6];
  const float* b1 = (const float*)d_in[7];
  const float* w_root2 = (const float*)d_in[8];
  const float* w_rel2 = (const float*)d_in[9];
  const float* b2 = (const float*)d_in[10];
  const float* clf_w = (const float*)d_in[11];
  const float* clf_b = (const float*)d_in[12];
  float* out = (float*)d_out;

  const int* src = edge_index;
  const int* dst = edge_index + NEDGES;

  u16* A1 = (u16*)d_ws;                      // NPAD * KA bf16
  u16* A2 = A1 + (size_t)NPAD * KA;          // NPAD * KA bf16
  u16* Bt = A2 + (size_t)NPAD * KA;          // 768 * KA bf16
  int* deg = (int*)(Bt + (size_t)DIM * KA);  // NBINS
  int* offs = deg + NBINS;                   // NBINS + 1
  int* cur = offs + NBINS + 1;               // NBINS
  int* perm = cur + NBINS;                   // NEDGES

  // CSR of edges by (rel, dst)
  clear_deg_kernel<<<(NBINS + 255) / 256, 256, 0, stream>>>(deg);
  hist_kernel<<<NEDGES / 256, 256, 0, stream>>>(dst, etype, deg);
  scan_kernel<<<1, 256, 0, stream>>>(deg, offs, cur);
  scatter_kernel<<<NEDGES / 256, 256, 0, stream>>>(src, dst, etype, cur, perm);

  // layer 1
  build_x_kernel<<<NNODES, 192, 0, stream>>>(doc_ids, pass_ids, embed, A1);
  gather_kernel<<<NBINS, 192, 0, stream>>>(A1, offs, perm, A1);
  conv_bt_kernel<<<dim3(KA / 32, DIM / 32), 256, 0, stream>>>(w_root1, w_rel1, Bt);
  gemm_kernel<<<408, 256, 0, stream>>>(A1, Bt, b1, A2);

  // layer 2
  gather_kernel<<<NBINS, 192, 0, stream>>>(A2, offs, perm, A2);
  conv_bt_kernel<<<dim3(KA / 32, DIM / 32), 256, 0, stream>>>(w_root2, w_rel2, Bt);
  gemm_kernel<<<408, 256, 0, stream>>>(A2, Bt, b2, A1);

  classify_kernel<<<NPASS, 192, 0, stream>>>(A1, clf_w, clf_b, out);
}

// Round 4
// 82.735 us; speedup vs baseline: 6.0574x; 1.2730x over previous
//
#include <hip/hip_runtime.h>

#define NDOCS 64
#define NPASS 1024
#define TITLE_LEN 128
#define SEQ 256
#define NEDGES 32768
#define NNODES 2112   // NDOCS + 2*NPASS
#define DIM 768
#define KA 2304       // 3*DIM fused K
#define NPAD 2176     // 34 * 64
#define SPAN_TOK 30522
#define NREL 2
#define NBINS (NREL * NNODES)  // 4224
#define BK 64
#define SPAN0 (NNODES - NPASS)  // 1088

typedef unsigned short u16;
typedef u16 u16x4 __attribute__((ext_vector_type(4)));
typedef __bf16 bf16x8 __attribute__((ext_vector_type(8)));
typedef float f32x4 __attribute__((ext_vector_type(4)));

__device__ inline u16 f2bf(float f) {
  unsigned u = __builtin_bit_cast(unsigned, f);
  u += 0x7FFFu + ((u >> 16) & 1u);
  return (u16)(u >> 16);
}
__device__ inline float bf2f(u16 h) {
  unsigned u = ((unsigned)h) << 16;
  return __builtin_bit_cast(float, u);
}
__device__ inline void gld16(const void* g, void* l) {
  __builtin_amdgcn_global_load_lds(
      (const __attribute__((address_space(1))) void*)g,
      (__attribute__((address_space(3))) void*)l, 16, 0, 0);
}

// ---------- node features -> bf16 x-slice of A1 ----------
__global__ __launch_bounds__(192) void build_x_kernel(
    const int* __restrict__ doc_ids, const int* __restrict__ pass_ids,
    const float* __restrict__ embed, u16* __restrict__ A1) {
  int node = blockIdx.x;
  int t = threadIdx.x;
  int tok;
  if (node < NDOCS) tok = doc_ids[node * TITLE_LEN];
  else if (node < NDOCS + NPASS) tok = pass_ids[(node - NDOCS) * SEQ];
  else tok = SPAN_TOK;
  float4 v = *reinterpret_cast<const float4*>(&embed[(size_t)tok * DIM + t * 4]);
  u16x4 o;
  o.x = f2bf(v.x); o.y = f2bf(v.y); o.z = f2bf(v.z); o.w = f2bf(v.w);
  *reinterpret_cast<u16x4*>(&A1[(size_t)node * KA + t * 4]) = o;
}

// ---------- CSR build ----------
__global__ __launch_bounds__(256) void clear_deg_kernel(int* __restrict__ deg) {
  int i = blockIdx.x * 256 + threadIdx.x;
  if (i < NBINS) deg[i] = 0;
}

__global__ __launch_bounds__(256) void hist_kernel(const int* __restrict__ dst,
                                                   const int* __restrict__ et,
                                                   int* __restrict__ deg) {
  int e = blockIdx.x * 256 + threadIdx.x;
  atomicAdd(&deg[et[e] * NNODES + dst[e]], 1);
}

__global__ __launch_bounds__(256) void scan_kernel(const int* __restrict__ deg,
                                                   int* __restrict__ offs,
                                                   int* __restrict__ cur) {
  __shared__ int part[256];
  int t = threadIdx.x;
  int loc[17];
  int s = 0;
#pragma unroll
  for (int i = 0; i < 17; ++i) {
    int idx = t * 17 + i;
    loc[i] = s;
    s += (idx < NBINS) ? deg[idx] : 0;
  }
  part[t] = s;
  __syncthreads();
  for (int off = 1; off < 256; off <<= 1) {
    int v = (t >= off) ? part[t - off] : 0;
    __syncthreads();
    part[t] += v;
    __syncthreads();
  }
  int pre = (t == 0) ? 0 : part[t - 1];
#pragma unroll
  for (int i = 0; i < 17; ++i) {
    int idx = t * 17 + i;
    if (idx <= NBINS) {
      int v = pre + loc[i];
      offs[idx] = v;
      if (idx < NBINS) cur[idx] = v;
    }
  }
}

__global__ __launch_bounds__(256) void scatter_kernel(
    const int* __restrict__ srcv, const int* __restrict__ dst,
    const int* __restrict__ et, int* __restrict__ cur, int* __restrict__ perm) {
  int e = blockIdx.x * 256 + threadIdx.x;
  int bin = et[e] * NNODES + dst[e];
  int p = atomicAdd(&cur[bin], 1);
  perm[p] = srcv[e];
}

// ---------- per-bin mean gather (layer 1): writes A1 num-slices ----------
__global__ __launch_bounds__(192) void gather_kernel(const u16* __restrict__ A,
                                                     const int* __restrict__ offs,
                                                     const int* __restrict__ perm,
                                                     u16* __restrict__ Anum) {
  int bin = blockIdx.x;  // r*NNODES + d
  int r = bin / NNODES;
  int d = bin - r * NNODES;
  int beg = offs[bin], end = offs[bin + 1];
  int t = threadIdx.x;
  float a0 = 0.f, a1 = 0.f, a2 = 0.f, a3 = 0.f;
  for (int i = beg; i < end; ++i) {
    int s = perm[i];
    u16x4 v = *reinterpret_cast<const u16x4*>(&A[(size_t)s * KA + t * 4]);
    a0 += bf2f(v.x); a1 += bf2f(v.y); a2 += bf2f(v.z); a3 += bf2f(v.w);
  }
  float inv = (end > beg) ? 1.0f / (float)(end - beg) : 0.0f;
  u16x4 o;
  o.x = f2bf(a0 * inv); o.y = f2bf(a1 * inv); o.z = f2bf(a2 * inv); o.w = f2bf(a3 * inv);
  *reinterpret_cast<u16x4*>(&Anum[(size_t)d * KA + DIM + (size_t)r * DIM + t * 4]) = o;
}

// ---------- weights -> Bt (N x K bf16, transposed) ----------
__global__ __launch_bounds__(256) void conv_bt_kernel(
    const float* __restrict__ w_root, const float* __restrict__ w_rel,
    u16* __restrict__ Bt) {
  __shared__ float tile[32][33];
  int k0 = blockIdx.x * 32, n0 = blockIdx.y * 32;
  int tx = threadIdx.x & 31, ty = threadIdx.x >> 5;  // 32 x 8
#pragma unroll
  for (int i = 0; i < 4; ++i) {
    int k = k0 + ty + 8 * i;
    const float* row = (k < DIM) ? (w_root + (size_t)k * DIM)
                                 : (w_rel + (size_t)(k - DIM) * DIM);
    tile[ty + 8 * i][tx] = row[n0 + tx];
  }
  __syncthreads();
#pragma unroll
  for (int i = 0; i < 4; ++i) {
    int n = n0 + ty + 8 * i;
    Bt[(size_t)n * KA + k0 + tx] = f2bf(tile[tx][ty + 8 * i]);
  }
}

// ---------- bf16 MFMA GEMM: out1[NPAD x 768] = A[NPAD x 2304] @ Bt^T + bias ----
// 64x64 tile, BK=64, 4 waves (2x2, 32x32 each), double-buffered LDS, 2-phase
// prefetch, XCD-swizzled 1D grid of 408. C is compact: ldc = DIM.
__global__ __launch_bounds__(256) void gemm_kernel(
    const u16* __restrict__ A, const u16* __restrict__ Bt,
    const float* __restrict__ bias, u16* __restrict__ C /* ldc = DIM */) {
  __shared__ u16 As[2][64 * BK];
  __shared__ u16 Bs[2][64 * BK];
  int wg = blockIdx.x;                  // 0..407, 408 = 8 XCDs * 51
  int swz = (wg & 7) * 51 + (wg >> 3);  // bijective: contiguous tiles per XCD
  int bm = swz / 12, bn = swz % 12;     // 34 x 12 tile grid
  int row0 = bm * 64, col0 = bn * 64;
  int tid = threadIdx.x;
  int lane = tid & 63, wid = tid >> 6;
  int wr = wid >> 1, wc = wid & 1;
  int l15 = lane & 15, l4 = lane >> 4;
  int sr = tid >> 3;  // staging row within 32-row chunk
  int sc = tid & 7;   // staging 16B slot
  f32x4 acc[2][2] = {};

#define STAGE(b, kbase)                                                         \
  {                                                                             \
    _Pragma("unroll") for (int h = 0; h < 2; ++h) {                             \
      int r = h * 32 + sr;                                                      \
      int kk = (sc ^ (r & 7)) * 8; /* pre-swizzled global source (rule #21) */  \
      gld16(&A[(size_t)(row0 + r) * KA + (kbase) + kk],                         \
            &As[b][h * 2048 + tid * 8]);                                        \
      gld16(&Bt[(size_t)(col0 + r) * KA + (kbase) + kk],                        \
            &Bs[b][h * 2048 + tid * 8]);                                        \
    }                                                                           \
  }

  STAGE(0, 0);
  __syncthreads();

  const int nt = KA / BK;  // 36
  for (int t = 0; t < nt; ++t) {
    int buf = t & 1;
    if (t + 1 < nt) STAGE(buf ^ 1, (t + 1) * BK);
    bf16x8 af[2][2], bg[2][2];
#pragma unroll
    for (int h = 0; h < 2; ++h) {
#pragma unroll
      for (int m = 0; m < 2; ++m) {
        int rl = wr * 32 + m * 16 + l15;
        int ck = (h * 4 + l4) ^ (rl & 7);
        af[h][m] = *reinterpret_cast<const bf16x8*>(&As[buf][rl * BK + ck * 8]);
        int cl = wc * 32 + m * 16 + l15;
        int ck2 = (h * 4 + l4) ^ (cl & 7);
        bg[h][m] = *reinterpret_cast<const bf16x8*>(&Bs[buf][cl * BK + ck2 * 8]);
      }
    }
#pragma unroll
    for (int h = 0; h < 2; ++h)
#pragma unroll
      for (int m = 0; m < 2; ++m)
#pragma unroll
        for (int n = 0; n < 2; ++n)
          acc[m][n] = __builtin_amdgcn_mfma_f32_16x16x32_bf16(af[h][m], bg[h][n],
                                                              acc[m][n], 0, 0, 0);
    __syncthreads();
  }
#undef STAGE

#pragma unroll
  for (int m = 0; m < 2; ++m) {
#pragma unroll
    for (int n = 0; n < 2; ++n) {
      int col = col0 + wc * 32 + n * 16 + l15;
      float b = bias[col];
#pragma unroll
      for (int q = 0; q < 4; ++q) {
        int row = row0 + wr * 32 + m * 16 + l4 * 4 + q;
        C[(size_t)row * DIM + col] = f2bf(acc[m][n][q] + b);
      }
    }
  }
}

// ---------- fold layer-2 weights into a vector: v = Wcat2 @ clf_w, v[2304]=c0 --
__global__ __launch_bounds__(64) void foldv_kernel(
    const float* __restrict__ w_root2, const float* __restrict__ w_rel2,
    const float* __restrict__ b2, const float* __restrict__ clf_w,
    const float* __restrict__ clf_b, float* __restrict__ v) {
  int k = blockIdx.x;  // 0 .. 3*DIM (inclusive; last = bias fold)
  int t = threadIdx.x;
  const float* row;
  if (k < DIM) row = w_root2 + (size_t)k * DIM;
  else if (k < 3 * DIM) row = w_rel2 + (size_t)(k - DIM) * DIM;  // (2,768,768) contiguous
  else row = b2;
  float s = 0.f;
  for (int j = t; j < DIM; j += 64) s += row[j] * clf_w[j];
#pragma unroll
  for (int off = 32; off > 0; off >>= 1) s += __shfl_down(s, off);
  if (t == 0) v[k] = s + (k == 3 * DIM ? clf_b[0] : 0.f);
}

// ---------- z init: root-path dot for span rows ----------
__global__ __launch_bounds__(64) void zroot_kernel(const u16* __restrict__ out1,
                                                   const float* __restrict__ v,
                                                   float* __restrict__ z) {
  int i = blockIdx.x;  // span idx 0..NPASS-1
  int t = threadIdx.x;
  const u16* xr = out1 + (size_t)(SPAN0 + i) * DIM;
  float s = 0.f;
#pragma unroll
  for (int it = 0; it < 3; ++it) {
    int j = t * 4 + it * 256;
    u16x4 a = *reinterpret_cast<const u16x4*>(&xr[j]);
    float4 w = *reinterpret_cast<const float4*>(&v[j]);
    s += bf2f(a.x) * w.x + bf2f(a.y) * w.y + bf2f(a.z) * w.z + bf2f(a.w) * w.w;
  }
#pragma unroll
  for (int off = 32; off > 0; off >>= 1) s += __shfl_down(s, off);
  if (t == 0) z[i] = s + v[3 * DIM];
}

// ---------- layer-2 gather fused with v-dot: z[d] += mean(out1[src]) . v_r ----
__global__ __launch_bounds__(192) void gather2_kernel(
    const u16* __restrict__ out1, const int* __restrict__ offs,
    const int* __restrict__ perm, const float* __restrict__ v,
    float* __restrict__ z) {
  int b = blockIdx.x;            // 0..2047: span bins only
  int r = b >> 10;               // relation
  int i = b & 1023;              // span idx
  int bin = r * NNODES + SPAN0 + i;
  int beg = offs[bin], end = offs[bin + 1];
  if (beg == end) return;
  int t = threadIdx.x;
  float a0 = 0.f, a1 = 0.f, a2 = 0.f, a3 = 0.f;
  for (int e = beg; e < end; ++e) {
    int s = perm[e];
    u16x4 x = *reinterpret_cast<const u16x4*>(&out1[(size_t)s * DIM + t * 4]);
    a0 += bf2f(x.x); a1 += bf2f(x.y); a2 += bf2f(x.z); a3 += bf2f(x.w);
  }
  float4 w = *reinterpret_cast<const float4*>(&v[DIM + r * DIM + t * 4]);
  float s = (a0 * w.x + a1 * w.y + a2 * w.z + a3 * w.w) / (float)(end - beg);
#pragma unroll
  for (int off = 32; off > 0; off >>= 1) s += __shfl_down(s, off);
  __shared__ float red[3];
  if ((t & 63) == 0) red[t >> 6] = s;
  __syncthreads();
  if (t == 0) atomicAdd(&z[i], red[0] + red[1] + red[2]);
}

// ---------- final activation ----------
__global__ __launch_bounds__(256) void final_kernel(const float* __restrict__ z,
                                                    float* __restrict__ out) {
  int i = blockIdx.x * 256 + threadIdx.x;
  if (i < NPASS) {
    float sc = 1.0f / (1.0f + expf(-z[i]));
    out[i] = expf(sc * 5.0f);  // exp(score / TAU), TAU = 0.2
  }
}

extern "C" void kernel_launch(void* const* d_in, const int* in_sizes, int n_in,
                              void* d_out, int out_size, void* d_ws, size_t ws_size,
                              hipStream_t stream) {
  const int* doc_ids = (const int*)d_in[0];
  const int* pass_ids = (const int*)d_in[1];
  const int* edge_index = (const int*)d_in[2];
  const int* etype = (const int*)d_in[3];
  const float* embed = (const float*)d_in[4];
  const float* w_root1 = (const float*)d_in[5];
  const float* w_rel1 = (const float*)d_in[6];
  const float* b1 = (const float*)d_in[7];
  const float* w_root2 = (const float*)d_in[8];
  const float* w_rel2 = (const float*)d_in[9];
  const float* b2 = (const float*)d_in[10];
  const float* clf_w = (const float*)d_in[11];
  const float* clf_b = (const float*)d_in[12];
  float* out = (float*)d_out;

  const int* src = edge_index;
  const int* dst = edge_index + NEDGES;

  u16* A1 = (u16*)d_ws;                        // NPAD * KA bf16
  u16* out1 = A1 + (size_t)NPAD * KA;          // NPAD * DIM bf16
  u16* Bt = out1 + (size_t)NPAD * DIM;         // DIM * KA bf16
  float* v = (float*)(Bt + (size_t)DIM * KA);  // 3*DIM + 1
  float* z = v + 3 * DIM + 1;                  // NPASS
  int* deg = (int*)(z + NPASS);                // NBINS
  int* offs = deg + NBINS;                     // NBINS + 1
  int* cur = offs + NBINS + 1;                 // NBINS
  int* perm = cur + NBINS;                     // NEDGES

  // CSR of edges by (rel, dst)
  clear_deg_kernel<<<(NBINS + 255) / 256, 256, 0, stream>>>(deg);
  hist_kernel<<<NEDGES / 256, 256, 0, stream>>>(dst, etype, deg);
  scan_kernel<<<1, 256, 0, stream>>>(deg, offs, cur);
  scatter_kernel<<<NEDGES / 256, 256, 0, stream>>>(src, dst, etype, cur, perm);

  // layer 1
  build_x_kernel<<<NNODES, 192, 0, stream>>>(doc_ids, pass_ids, embed, A1);
  gather_kernel<<<NBINS, 192, 0, stream>>>(A1, offs, perm, A1);
  conv_bt_kernel<<<dim3(KA / 32, DIM / 32), 256, 0, stream>>>(w_root1, w_rel1, Bt);
  gemm_kernel<<<408, 256, 0, stream>>>(A1, Bt, b1, out1);

  // layer 2 folded into a matvec (z = A2 @ (Wcat2 @ clf_w) + const)
  foldv_kernel<<<3 * DIM + 1, 64, 0, stream>>>(w_root2, w_rel2, b2, clf_w, clf_b, v);
  zroot_kernel<<<NPASS, 64, 0, stream>>>(out1, v, z);
  gather2_kernel<<<2 * NPASS, 192, 0, stream>>>(out1, offs, perm, v, z);
  final_kernel<<<(NPASS + 255) / 256, 256, 0, stream>>>(z, out);
}